// Round 6
// baseline (287.301 us; speedup 1.0000x reference)
//
#include <hip/hip_runtime.h>
#include <hip/hip_bf16.h>
#include <cstdint>
#include <cstddef>

// StreamingAttentionBlock: B=2, T=2048, DIM=1024, H=16, hd=64, window=3 keys
// I/O: fp32. Internal: bf16 MFMA, fp32 accum. (R2-R4 passed: absmax 0.0156)
// R6: single 512-block megakernel, software grid barrier (device-scope atomics
// + __threadfence). 2 blocks/CU is resource-guaranteed (VGPR<=256, LDS 40KB)
// so all 512 blocks are co-resident -> no deadlock, no cooperative-API veto.
#define T_SEQ 2048
#define DIMSZ 1024
#define NBLK 512

typedef float f32x4 __attribute__((ext_vector_type(4)));
typedef short bf16x8 __attribute__((ext_vector_type(8)));

// async global->LDS, 16B per lane. LDS dest = wave-uniform base + lane*16.
__device__ __forceinline__ void gld_lds16(const __hip_bfloat16* g, __hip_bfloat16* l) {
    __builtin_amdgcn_global_load_lds(
        (const __attribute__((address_space(1))) unsigned int*)g,
        (__attribute__((address_space(3))) unsigned int*)l,
        16, 0, 0);
}

__device__ __forceinline__ float bf2f(unsigned short u) {
    union { unsigned int i; float f; } c; c.i = (unsigned int)u << 16; return c.f;
}

// sense-forward centralized barrier; gen monotonically 0->1->2->3.
// __threadfence() = agent scope: on gfx950 emits L2 writeback/invalidate needed
// for cross-XCD store visibility (same mechanism that makes G12 atomics work).
__device__ __forceinline__ void grid_barrier(int* cnt, int* gen, int target) {
    __syncthreads();
    if (threadIdx.x == 0) {
        __threadfence();                         // release: drain + flush stores
        if (atomicAdd(cnt, 1) == NBLK - 1) {
            atomicExch(cnt, 0);                  // reset before release
            __threadfence();
            atomicExch(gen, target);
        } else {
            while (atomicAdd(gen, 0) < target) { }   // atomic load spin
        }
        __threadfence();                         // acquire: invalidate caches
    }
    __syncthreads();
}

__global__ __launch_bounds__(256, 2) void mega(
    const float* __restrict__ x,      __hip_bfloat16* __restrict__ xb,
    const float* __restrict__ wqkv,   __hip_bfloat16* __restrict__ wqkvT,
    const float* __restrict__ wproj,  __hip_bfloat16* __restrict__ wprojT,
    __hip_bfloat16* __restrict__ qkv, __hip_bfloat16* __restrict__ attn,
    const float* __restrict__ bias,   float* __restrict__ out,
    int* __restrict__ bar)
{
    __shared__ __align__(16) char smem[40960];   // GEMM1 phase: As 16KB + Bs 24KB
    const int bid  = blockIdx.x;
    const int tid  = threadIdx.x;
    const int wv   = tid >> 6;
    const int lane = tid & 63;
    int* cnt = bar;
    int* gen = bar + 16;   // separate cache lines

    // ============ phase 0: prep (x->bf16; weights convert+transpose) ==========
    {
        float (*tile)[33] = (float(*)[33])smem;
        for (int u = bid; u < 8192; u += NBLK) {
            if (u < 4096) {
                int i = (u * 256 + tid) * 4;
                float4 v = *(const float4*)(x + i);
                union { __hip_bfloat16 h[4]; ushort4 uu; } pk;
                pk.h[0] = __hip_bfloat16(v.x); pk.h[1] = __hip_bfloat16(v.y);
                pk.h[2] = __hip_bfloat16(v.z); pk.h[3] = __hip_bfloat16(v.w);
                *(ushort4*)(xb + i) = pk.uu;
            } else {
                const float* in; __hip_bfloat16* o; int C, c0, r0;
                if (u < 7168) {
                    int bb = u - 4096; in = wqkv; o = wqkvT; C = 3072;
                    c0 = (bb % 96) * 32; r0 = (bb / 96) * 32;
                } else {
                    int bb = u - 7168; in = wproj; o = wprojT; C = 1024;
                    c0 = (bb & 31) * 32; r0 = (bb >> 5) * 32;
                }
                const int tx = tid & 31, ty = tid >> 5;
                __syncthreads();   // WAR vs previous iteration's tile reads
#pragma unroll
                for (int p = 0; p < 32; p += 8)
                    tile[ty + p][tx] = in[(size_t)(r0 + ty + p) * C + c0 + tx];
                __syncthreads();
#pragma unroll
                for (int p = 0; p < 32; p += 8)
                    o[(size_t)(c0 + ty + p) * 1024 + r0 + tx] = __hip_bfloat16(tile[tx][ty + p]);
            }
        }
    }
    grid_barrier(cnt, gen, 1);

    // ============ phase 1: qkv = xb @ wqkvT^T (4096x3072, K=1024) =============
    // 128x192 tile -> exactly 512 tiles (32 bm x 16 bn), BK=64 (two 32-wide
    // m97-style sub-tiles). Wave = 64m x 96n via 4x6 MFMA 16x16x32.
    {
        __hip_bfloat16* As = (__hip_bfloat16*)smem;             // 2*128*32 = 16 KB
        __hip_bfloat16* Bs = (__hip_bfloat16*)(smem + 16384);   // 2*192*32 = 24 KB
        const int bn = bid & 15, bm = bid >> 4;
        const int wm = wv >> 1, wn = wv & 1;

        f32x4 acc[4][6] = {};
        const int srow = lane >> 2;          // 0..15
        const int scol = (lane & 3) * 8;     // 16B per lane
        const __hip_bfloat16* Ag = xb    + (size_t)(bm * 128) * 1024;
        const __hip_bfloat16* Bg = wqkvT + (size_t)(bn * 192) * 1024;
        const int fm = lane & 15;
        const int fq = (lane >> 4) * 8;

        for (int kk = 0; kk < 1024; kk += 64) {
#pragma unroll
            for (int kh = 0; kh < 2; ++kh) {
#pragma unroll
                for (int it = 0; it < 2; ++it) {          // A: 128 rows
                    int row = (it * 4 + wv) * 16 + srow;
                    gld_lds16(Ag + (size_t)row * 1024 + kk + kh * 32 + scol,
                              As + kh * 4096 + row * 32 + scol);
                }
#pragma unroll
                for (int it = 0; it < 3; ++it) {          // B: 192 rows
                    int row = (it * 4 + wv) * 16 + srow;
                    gld_lds16(Bg + (size_t)row * 1024 + kk + kh * 32 + scol,
                              Bs + kh * 6144 + row * 32 + scol);
                }
            }
            __syncthreads();

#pragma unroll
            for (int kh = 0; kh < 2; ++kh) {
                bf16x8 af[4], bfr[6];
#pragma unroll
                for (int i = 0; i < 4; ++i)
                    af[i] = *(const bf16x8*)(As + kh * 4096 + (wm * 64 + i * 16 + fm) * 32 + fq);
#pragma unroll
                for (int j = 0; j < 6; ++j)
                    bfr[j] = *(const bf16x8*)(Bs + kh * 6144 + (wn * 96 + j * 16 + fm) * 32 + fq);
#pragma unroll
                for (int i = 0; i < 4; ++i)
#pragma unroll
                    for (int j = 0; j < 6; ++j)
                        acc[i][j] = __builtin_amdgcn_mfma_f32_16x16x32_bf16(af[i], bfr[j], acc[i][j], 0, 0, 0);
            }
            __syncthreads();
        }

        // C/D layout: col=lane&15, row=(lane>>4)*4+reg  [m89-verified]
        const int fcol  = lane & 15;
        const int frow4 = (lane >> 4) * 4;
        const int cm0 = bm * 128 + wm * 64;
        const int cn0 = bn * 192 + wn * 96;
#pragma unroll
        for (int j = 0; j < 6; ++j) {
            int col = cn0 + j * 16 + fcol;
#pragma unroll
            for (int i = 0; i < 4; ++i)
#pragma unroll
                for (int r = 0; r < 4; ++r) {
                    int row = cm0 + i * 16 + frow4 + r;
                    qkv[(size_t)row * 3072 + col] = __hip_bfloat16(acc[i][j][r]);
                }
        }
    }
    grid_barrier(cnt, gen, 2);

    // ============ phase 2: banded attention (3-key window) ====================
    for (int r = bid; r < 4096; r += NBLK) {
        const int t  = r & (T_SEQ - 1);
        const size_t rb = (size_t)r * (3 * DIMSZ);
        const int d0 = tid * 4;

        ushort4 qu = *(const ushort4*)(qkv + rb + d0);
        float q0 = bf2f(qu.x), q1 = bf2f(qu.y), q2 = bf2f(qu.z), q3 = bf2f(qu.w);

        float s[3], vvx[3], vvy[3], vvz[3], vvw[3];
#pragma unroll
        for (int j = 0; j < 3; ++j) {
            bool ok = (t + j) < T_SEQ;       // masks seq end (and batch boundary)
            size_t rbj = ok ? rb + (size_t)j * (3 * DIMSZ) : rb;
            ushort4 ku = *(const ushort4*)(qkv + rbj + DIMSZ + d0);
            ushort4 vu = *(const ushort4*)(qkv + rbj + 2 * DIMSZ + d0);
            vvx[j] = bf2f(vu.x); vvy[j] = bf2f(vu.y); vvz[j] = bf2f(vu.z); vvw[j] = bf2f(vu.w);
            float d = q0 * bf2f(ku.x) + q1 * bf2f(ku.y) + q2 * bf2f(ku.z) + q3 * bf2f(ku.w);
#pragma unroll
            for (int off = 8; off > 0; off >>= 1)
                d += __shfl_xor(d, off, 64); // reduce within 16-lane head group
            s[j] = ok ? d * 0.125f : -1e30f; // scale = 64^-0.5
        }
        float m  = fmaxf(s[0], fmaxf(s[1], s[2]));
        float p0 = __expf(s[0] - m), p1 = __expf(s[1] - m), p2 = __expf(s[2] - m);
        float inv = 1.0f / (p0 + p1 + p2);
        union { __hip_bfloat16 h[4]; ushort4 uu; } pk;
        pk.h[0] = __hip_bfloat16((p0 * vvx[0] + p1 * vvx[1] + p2 * vvx[2]) * inv);
        pk.h[1] = __hip_bfloat16((p0 * vvy[0] + p1 * vvy[1] + p2 * vvy[2]) * inv);
        pk.h[2] = __hip_bfloat16((p0 * vvz[0] + p1 * vvz[1] + p2 * vvz[2]) * inv);
        pk.h[3] = __hip_bfloat16((p0 * vvw[0] + p1 * vvw[1] + p2 * vvw[2]) * inv);
        *(ushort4*)(attn + (size_t)r * DIMSZ + d0) = pk.uu;
    }
    grid_barrier(cnt, gen, 3);

    // ============ phase 3: out = attn @ wprojT^T + bias (4096x1024) ===========
    // 64x128 tile, BK=64 -> exactly 512 tiles (64 bm x 8 bn).
    {
        __hip_bfloat16* As = (__hip_bfloat16*)smem;             // 2*64*32 = 8 KB
        __hip_bfloat16* Bs = (__hip_bfloat16*)(smem + 8192);    // 2*128*32 = 16 KB
        const int bn = bid & 7, bm = bid >> 3;
        const int wm = wv >> 1, wn = wv & 1;

        f32x4 acc[2][4] = {};
        const int srow = lane >> 2;
        const int scol = (lane & 3) * 8;
        const __hip_bfloat16* Ag = attn   + (size_t)(bm * 64) * 1024;
        const __hip_bfloat16* Bg = wprojT + (size_t)(bn * 128) * 1024;
        const int fm = lane & 15;
        const int fq = (lane >> 4) * 8;

        for (int kk = 0; kk < 1024; kk += 64) {
#pragma unroll
            for (int kh = 0; kh < 2; ++kh) {
                {
                    int row = wv * 16 + srow;                     // 0..63
                    gld_lds16(Ag + (size_t)row * 1024 + kk + kh * 32 + scol,
                              As + kh * 2048 + row * 32 + scol);
                }
#pragma unroll
                for (int it = 0; it < 2; ++it) {
                    int row = (it * 4 + wv) * 16 + srow;          // 0..127
                    gld_lds16(Bg + (size_t)row * 1024 + kk + kh * 32 + scol,
                              Bs + kh * 4096 + row * 32 + scol);
                }
            }
            __syncthreads();

#pragma unroll
            for (int kh = 0; kh < 2; ++kh) {
                bf16x8 af[2], bfr[4];
#pragma unroll
                for (int i = 0; i < 2; ++i)
                    af[i] = *(const bf16x8*)(As + kh * 2048 + (wm * 32 + i * 16 + fm) * 32 + fq);
#pragma unroll
                for (int j = 0; j < 4; ++j)
                    bfr[j] = *(const bf16x8*)(Bs + kh * 4096 + (wn * 64 + j * 16 + fm) * 32 + fq);
#pragma unroll
                for (int i = 0; i < 2; ++i)
#pragma unroll
                    for (int j = 0; j < 4; ++j)
                        acc[i][j] = __builtin_amdgcn_mfma_f32_16x16x32_bf16(af[i], bfr[j], acc[i][j], 0, 0, 0);
            }
            __syncthreads();
        }

        const int fcol  = lane & 15;
        const int frow4 = (lane >> 4) * 4;
        const int cm0 = bm * 64 + wm * 32;
        const int cn0 = bn * 128 + wn * 64;
#pragma unroll
        for (int j = 0; j < 4; ++j) {
            int col = cn0 + j * 16 + fcol;
            float bv = bias[col];
#pragma unroll
            for (int i = 0; i < 2; ++i)
#pragma unroll
                for (int r = 0; r < 4; ++r) {
                    int row = cm0 + i * 16 + frow4 + r;
                    out[(size_t)row * 1024 + col] = acc[i][j][r] + bv;
                }
        }
    }
}

extern "C" void kernel_launch(void* const* d_in, const int* in_sizes, int n_in,
                              void* d_out, int out_size, void* d_ws, size_t ws_size,
                              hipStream_t stream) {
    const float* x      = (const float*)d_in[0];  // (B,T,DIM) fp32
    const float* w_qkv  = (const float*)d_in[1];  // (DIM, 3*DIM) fp32
    const float* w_proj = (const float*)d_in[2];  // (DIM, DIM) fp32
    const float* b_proj = (const float*)d_in[3];  // (DIM,) fp32
    float* out = (float*)d_out;                   // (B,T,DIM) fp32

    // workspace:
    //   [0,8M)    xb (x bf16) -> reused as attn output after phase 1 consumes it
    //   [8M,14M)  wqkvT  (3072x1024)
    //   [14M,16M) wprojT (1024x1024)
    //   [16M,40M) qkv    (4096x3072)
    //   [40M,+)   barrier state (zeroed per launch via hipMemsetAsync)
    char* ws = (char*)d_ws;
    __hip_bfloat16* xb     = (__hip_bfloat16*)(ws);
    __hip_bfloat16* attn   = (__hip_bfloat16*)(ws);            // reuse of xb region
    __hip_bfloat16* wqkvT  = (__hip_bfloat16*)(ws + (8u  << 20));
    __hip_bfloat16* wprojT = (__hip_bfloat16*)(ws + (14u << 20));
    __hip_bfloat16* qkv    = (__hip_bfloat16*)(ws + (16u << 20));
    int* bar               = (int*)(ws + (40u << 20));

    hipMemsetAsync(bar, 0, 256, stream);   // zero barrier cnt/gen (ws is poisoned)

    mega<<<NBLK, 256, 0, stream>>>(x, xb, w_qkv, wqkvT, w_proj, wprojT,
                                   qkv, attn, b_proj, out, bar);
}

// Round 8
// 150.184 us; speedup vs baseline: 1.9130x; 1.9130x over previous
//
#include <hip/hip_runtime.h>
#include <hip/hip_bf16.h>
#include <cstdint>
#include <cstddef>

// StreamingAttentionBlock: B=2, T=2048, DIM=1024, H=16, hd=64, window=3 keys
// I/O: fp32. Internal: bf16 MFMA, fp32 accum.
// R8 = R7 minus the stray NBATCH_M() compile error: R4 4-kernel structure with
// 32x32x16 MFMA replacing 16x16x32 (m119: 15% better FLOP/cycle, identical
// staging/ds_read/barrier structure).
#define T_SEQ 2048
#define DIMSZ 1024

typedef float f32x16 __attribute__((ext_vector_type(16)));
typedef short bf16x8 __attribute__((ext_vector_type(8)));

// async global->LDS, 16B per lane. LDS dest = wave-uniform base + lane*16.
__device__ __forceinline__ void gld_lds16(const __hip_bfloat16* g, __hip_bfloat16* l) {
    __builtin_amdgcn_global_load_lds(
        (const __attribute__((address_space(1))) unsigned int*)g,
        (__attribute__((address_space(3))) unsigned int*)l,
        16, 0, 0);
}

__device__ __forceinline__ float bf2f(unsigned short u) {
    union { unsigned int i; float f; } c; c.i = (unsigned int)u << 16; return c.f;
}

// -------- fused prep: convert x -> bf16; convert+transpose both weights --------
__global__ __launch_bounds__(256) void prep(
    const float* __restrict__ x,      __hip_bfloat16* __restrict__ xb,
    const float* __restrict__ wqkv,   __hip_bfloat16* __restrict__ wqkvT,
    const float* __restrict__ wproj,  __hip_bfloat16* __restrict__ wprojT)
{
    __shared__ float tile[32][33];
    const int b = blockIdx.x;
    if (b < 4096) {
        int i = (b * 256 + threadIdx.x) * 4;
        float4 v = *(const float4*)(x + i);
        union { __hip_bfloat16 h[4]; ushort4 u; } pk;
        pk.h[0] = __hip_bfloat16(v.x); pk.h[1] = __hip_bfloat16(v.y);
        pk.h[2] = __hip_bfloat16(v.z); pk.h[3] = __hip_bfloat16(v.w);
        *(ushort4*)(xb + i) = pk.u;
        return;
    }
    const float* in; __hip_bfloat16* out; int C, c0, r0;
    if (b < 7168) {
        int bb = b - 4096; in = wqkv; out = wqkvT; C = 3072;
        c0 = (bb % 96) * 32; r0 = (bb / 96) * 32;
    } else {
        int bb = b - 7168; in = wproj; out = wprojT; C = 1024;
        c0 = (bb & 31) * 32; r0 = (bb >> 5) * 32;
    }
    const int tx = threadIdx.x & 31, ty = threadIdx.x >> 5;
#pragma unroll
    for (int p = 0; p < 32; p += 8)
        tile[ty + p][tx] = in[(size_t)(r0 + ty + p) * C + c0 + tx];
    __syncthreads();
#pragma unroll
    for (int p = 0; p < 32; p += 8)
        out[(size_t)(c0 + ty + p) * 1024 + r0 + tx] = __hip_bfloat16(tile[tx][ty + p]);
}

// -------- GEMM1: 128x128 tile, BK=64 (two 32-wide sub-tiles), 32x32x16 MFMA ----
// 4 waves (2x2); wave = 64x64 = 2x2 tiles of 32x32. A/B frag: row=lane&31,
// k-offset=(lane>>5)*8 (K=16 analog of the verified K=32 pattern).
__global__ __launch_bounds__(256) void gemm_bt_128(
    const __hip_bfloat16* __restrict__ A,
    const __hip_bfloat16* __restrict__ Bt,
    __hip_bfloat16* __restrict__ C,
    int M, int N, int K)
{
    __shared__ __align__(16) __hip_bfloat16 As[2 * 128 * 32];
    __shared__ __align__(16) __hip_bfloat16 Bs[2 * 128 * 32];

    const int tid  = threadIdx.x;
    const int wv   = tid >> 6;
    const int lane = tid & 63;
    const int bn   = blockIdx.x, bm = blockIdx.y;
    const int wm   = wv >> 1, wn = wv & 1;

    f32x16 acc[2][2] = {};

    const int srow = lane >> 2;          // 0..15
    const int scol = (lane & 3) * 8;     // 16B per lane

    const __hip_bfloat16* Ag = A  + (size_t)(bm * 128) * K;
    const __hip_bfloat16* Bg = Bt + (size_t)(bn * 128) * K;

    const int fm = lane & 31;            // row within 32-row MFMA tile
    const int fk = (lane >> 5) * 8;      // k-offset: 0 or 8

    for (int kk = 0; kk < K; kk += 64) {
#pragma unroll
        for (int kh = 0; kh < 2; ++kh)
#pragma unroll
            for (int it = 0; it < 2; ++it) {
                int row = (it * 4 + wv) * 16 + srow;          // 0..127
                gld_lds16(Ag + (size_t)row * K + kk + kh * 32 + scol,
                          As + kh * 4096 + row * 32 + scol);
                gld_lds16(Bg + (size_t)row * K + kk + kh * 32 + scol,
                          Bs + kh * 4096 + row * 32 + scol);
            }
        __syncthreads();

#pragma unroll
        for (int kh = 0; kh < 2; ++kh)
#pragma unroll
            for (int s = 0; s < 2; ++s) {     // two K=16 steps per 32-wide sub-tile
                const int ko = s * 16 + fk;
                bf16x8 a0 = *(const bf16x8*)(As + kh * 4096 + (wm * 64 +      fm) * 32 + ko);
                bf16x8 a1 = *(const bf16x8*)(As + kh * 4096 + (wm * 64 + 32 + fm) * 32 + ko);
                bf16x8 b0 = *(const bf16x8*)(Bs + kh * 4096 + (wn * 64 +      fm) * 32 + ko);
                bf16x8 b1 = *(const bf16x8*)(Bs + kh * 4096 + (wn * 64 + 32 + fm) * 32 + ko);
                acc[0][0] = __builtin_amdgcn_mfma_f32_32x32x16_bf16(a0, b0, acc[0][0], 0, 0, 0);
                acc[0][1] = __builtin_amdgcn_mfma_f32_32x32x16_bf16(a0, b1, acc[0][1], 0, 0, 0);
                acc[1][0] = __builtin_amdgcn_mfma_f32_32x32x16_bf16(a1, b0, acc[1][0], 0, 0, 0);
                acc[1][1] = __builtin_amdgcn_mfma_f32_32x32x16_bf16(a1, b1, acc[1][1], 0, 0, 0);
            }
        __syncthreads();
    }

    // 32x32 C/D layout [m74/m101-verified]: col=lane&31,
    // row=(reg&3)+8*(reg>>2)+4*(lane>>5)
    const int ccol  = lane & 31;
    const int rbase = 4 * (lane >> 5);
    const int cm0 = bm * 128 + wm * 64;
    const int cn0 = bn * 128 + wn * 64;
#pragma unroll
    for (int i = 0; i < 2; ++i)
#pragma unroll
        for (int j = 0; j < 2; ++j) {
            int col = cn0 + j * 32 + ccol;
#pragma unroll
            for (int r = 0; r < 16; ++r) {
                int row = cm0 + i * 32 + (r & 3) + 8 * (r >> 2) + rbase;
                C[(size_t)row * N + col] = __hip_bfloat16(acc[i][j][r]);
            }
        }
}

// -------- GEMM2: 64x128 tile, BK=64, 32x32x16 MFMA, fp32 out + bias ----------
// 4 waves (2x2); wave = 32x64 = 1x2 tiles of 32x32. 512 blocks = 2/CU.
__global__ __launch_bounds__(256) void gemm_bt_64(
    const __hip_bfloat16* __restrict__ A,
    const __hip_bfloat16* __restrict__ Bt,
    const float* __restrict__ bias,
    float* __restrict__ C,
    int M, int N, int K)
{
    __shared__ __align__(16) __hip_bfloat16 As[2 * 64 * 32];
    __shared__ __align__(16) __hip_bfloat16 Bs[2 * 128 * 32];

    const int tid  = threadIdx.x;
    const int wv   = tid >> 6;
    const int lane = tid & 63;
    const int bn   = blockIdx.x, bm = blockIdx.y;
    const int wm   = wv >> 1, wn = wv & 1;

    f32x16 acc[2] = {};

    const int srow = lane >> 2;
    const int scol = (lane & 3) * 8;

    const __hip_bfloat16* Ag = A  + (size_t)(bm * 64) * K;
    const __hip_bfloat16* Bg = Bt + (size_t)(bn * 128) * K;

    const int fm = lane & 31;
    const int fk = (lane >> 5) * 8;

    for (int kk = 0; kk < K; kk += 64) {
#pragma unroll
        for (int kh = 0; kh < 2; ++kh) {
            {
                int row = wv * 16 + srow;                     // 0..63
                gld_lds16(Ag + (size_t)row * K + kk + kh * 32 + scol,
                          As + kh * 2048 + row * 32 + scol);
            }
#pragma unroll
            for (int it = 0; it < 2; ++it) {
                int row = (it * 4 + wv) * 16 + srow;          // 0..127
                gld_lds16(Bg + (size_t)row * K + kk + kh * 32 + scol,
                          Bs + kh * 4096 + row * 32 + scol);
            }
        }
        __syncthreads();

#pragma unroll
        for (int kh = 0; kh < 2; ++kh)
#pragma unroll
            for (int s = 0; s < 2; ++s) {
                const int ko = s * 16 + fk;
                bf16x8 a0 = *(const bf16x8*)(As + kh * 2048 + (wm * 32 +      fm) * 32 + ko);
                bf16x8 b0 = *(const bf16x8*)(Bs + kh * 4096 + (wn * 64 +      fm) * 32 + ko);
                bf16x8 b1 = *(const bf16x8*)(Bs + kh * 4096 + (wn * 64 + 32 + fm) * 32 + ko);
                acc[0] = __builtin_amdgcn_mfma_f32_32x32x16_bf16(a0, b0, acc[0], 0, 0, 0);
                acc[1] = __builtin_amdgcn_mfma_f32_32x32x16_bf16(a0, b1, acc[1], 0, 0, 0);
            }
        __syncthreads();
    }

    const int ccol  = lane & 31;
    const int rbase = 4 * (lane >> 5);
    const int cm0 = bm * 64 + wm * 32;
    const int cn0 = bn * 128 + wn * 64;
#pragma unroll
    for (int j = 0; j < 2; ++j) {
        int col = cn0 + j * 32 + ccol;
        float bv = bias[col];
#pragma unroll
        for (int r = 0; r < 16; ++r) {
            int row = cm0 + (r & 3) + 8 * (r >> 2) + rbase;
            C[(size_t)row * N + col] = acc[j][r] + bv;
        }
    }
}

// -------- banded attention: one block per token; thread = 4-dim chunk --------
__global__ __launch_bounds__(256) void attn_banded(
    const __hip_bfloat16* __restrict__ qkv,   // (B*T, 3*DIM): [q | k | v]
    __hip_bfloat16* __restrict__ o)           // (B*T, DIM)
{
    const int t4 = threadIdx.x;          // dim-chunk index: dims [4*t4, 4*t4+4)
    const int r  = blockIdx.x;           // b*T + t
    const int t  = r & (T_SEQ - 1);
    const size_t rb = (size_t)r * (3 * DIMSZ);
    const int d0 = t4 * 4;

    ushort4 qu = *(const ushort4*)(qkv + rb + d0);
    float q0 = bf2f(qu.x), q1 = bf2f(qu.y), q2 = bf2f(qu.z), q3 = bf2f(qu.w);

    float s[3], vvx[3], vvy[3], vvz[3], vvw[3];
#pragma unroll
    for (int j = 0; j < 3; ++j) {
        bool ok = (t + j) < T_SEQ;       // masks seq end (and batch boundary)
        size_t rbj = ok ? rb + (size_t)j * (3 * DIMSZ) : rb;
        ushort4 ku = *(const ushort4*)(qkv + rbj + DIMSZ + d0);
        ushort4 vu = *(const ushort4*)(qkv + rbj + 2 * DIMSZ + d0);
        vvx[j] = bf2f(vu.x); vvy[j] = bf2f(vu.y); vvz[j] = bf2f(vu.z); vvw[j] = bf2f(vu.w);
        float d = q0 * bf2f(ku.x) + q1 * bf2f(ku.y) + q2 * bf2f(ku.z) + q3 * bf2f(ku.w);
#pragma unroll
        for (int off = 8; off > 0; off >>= 1)
            d += __shfl_xor(d, off, 64); // reduce within 16-lane head group
        s[j] = ok ? d * 0.125f : -1e30f; // scale = 64^-0.5
    }
    float m  = fmaxf(s[0], fmaxf(s[1], s[2]));
    float p0 = __expf(s[0] - m), p1 = __expf(s[1] - m), p2 = __expf(s[2] - m);
    float inv = 1.0f / (p0 + p1 + p2);
    union { __hip_bfloat16 h[4]; ushort4 uu; } pk;
    pk.h[0] = __hip_bfloat16((p0 * vvx[0] + p1 * vvx[1] + p2 * vvx[2]) * inv);
    pk.h[1] = __hip_bfloat16((p0 * vvy[0] + p1 * vvy[1] + p2 * vvy[2]) * inv);
    pk.h[2] = __hip_bfloat16((p0 * vvz[0] + p1 * vvz[1] + p2 * vvz[2]) * inv);
    pk.h[3] = __hip_bfloat16((p0 * vvw[0] + p1 * vvw[1] + p2 * vvw[2]) * inv);
    *(ushort4*)(o + (size_t)r * DIMSZ + d0) = pk.uu;
}

extern "C" void kernel_launch(void* const* d_in, const int* in_sizes, int n_in,
                              void* d_out, int out_size, void* d_ws, size_t ws_size,
                              hipStream_t stream) {
    const float* x      = (const float*)d_in[0];  // (B,T,DIM) fp32
    const float* w_qkv  = (const float*)d_in[1];  // (DIM, 3*DIM) fp32
    const float* w_proj = (const float*)d_in[2];  // (DIM, DIM) fp32
    const float* b_proj = (const float*)d_in[3];  // (DIM,) fp32
    float* out = (float*)d_out;                   // (B,T,DIM) fp32

    const int Mrows = 2 * T_SEQ;   // 4096

    // workspace (bf16 intermediates):
    //   [0,8M)    xb (x bf16) -> reused as attn output after GEMM1 consumes it
    //   [8M,14M)  wqkvT  (3072x1024)
    //   [14M,16M) wprojT (1024x1024)
    //   [16M,40M) qkv    (4096x3072)
    char* ws = (char*)d_ws;
    __hip_bfloat16* xb     = (__hip_bfloat16*)(ws);
    __hip_bfloat16* attn   = (__hip_bfloat16*)(ws);            // reuse of xb region
    __hip_bfloat16* wqkvT  = (__hip_bfloat16*)(ws + (8u  << 20));
    __hip_bfloat16* wprojT = (__hip_bfloat16*)(ws + (14u << 20));
    __hip_bfloat16* qkv    = (__hip_bfloat16*)(ws + (16u << 20));

    // 1) fused prep: x->bf16, both weight convert+transposes
    prep<<<8192, 256, 0, stream>>>(x, xb, w_qkv, wqkvT, w_proj, wprojT);

    // 2) qkv = x @ w_qkv   (4096 x 3072, K=1024): 24x32=768 blocks = 3/CU
    gemm_bt_128<<<dim3(3 * DIMSZ / 128, Mrows / 128), 256, 0, stream>>>(
        xb, wqkvT, qkv, Mrows, 3 * DIMSZ, DIMSZ);

    // 3) banded attention (3-key window) -> bf16 attn (reuses xb region)
    attn_banded<<<Mrows, 256, 0, stream>>>(qkv, attn);

    // 4) out = attn @ w_proj + b_proj  (4096 x 1024): 8x64=512 blocks = 2/CU
    gemm_bt_64<<<dim3(DIMSZ / 128, Mrows / 64), 256, 0, stream>>>(
        attn, wprojT, b_proj, out, Mrows, DIMSZ, DIMSZ);
}

// Round 9
// 143.876 us; speedup vs baseline: 1.9969x; 1.0438x over previous
//
#include <hip/hip_runtime.h>
#include <hip/hip_bf16.h>
#include <cstdint>
#include <cstddef>

// StreamingAttentionBlock: B=2, T=2048, DIM=1024, H=16, hd=64, window=3 keys
// I/O: fp32. Internal: bf16 MFMA, fp32 accumulation.
// R9 = exact revert to R4 (145.2 us best-known):
//   - R6 megakernel: +55us per software grid barrier (atomic spin serialization) — abandoned
//   - R8 32x32x16 MFMA: -5us regression (LDS fragment-read conflict pattern) — abandoned
// 16x16x32 MFMA + m97-style staging is the measured HIP-source plateau.
#define T_SEQ 2048
#define NBATCH 2
#define DIMSZ 1024
#define NHEAD 16
#define HDIM 64

typedef float f32x4 __attribute__((ext_vector_type(4)));
typedef short bf16x8 __attribute__((ext_vector_type(8)));

// async global->LDS, 16B per lane. LDS dest = wave-uniform base + lane*16.
__device__ __forceinline__ void gld_lds16(const __hip_bfloat16* g, __hip_bfloat16* l) {
    __builtin_amdgcn_global_load_lds(
        (const __attribute__((address_space(1))) unsigned int*)g,
        (__attribute__((address_space(3))) unsigned int*)l,
        16, 0, 0);
}

__device__ __forceinline__ float bf2f(unsigned short u) {
    union { unsigned int i; float f; } c; c.i = (unsigned int)u << 16; return c.f;
}

// -------- fused prep: convert x -> bf16; convert+transpose both weights --------
__global__ __launch_bounds__(256) void prep(
    const float* __restrict__ x,      __hip_bfloat16* __restrict__ xb,
    const float* __restrict__ wqkv,   __hip_bfloat16* __restrict__ wqkvT,
    const float* __restrict__ wproj,  __hip_bfloat16* __restrict__ wprojT)
{
    __shared__ float tile[32][33];
    const int b = blockIdx.x;
    if (b < 4096) {
        int i = (b * 256 + threadIdx.x) * 4;
        float4 v = *(const float4*)(x + i);
        union { __hip_bfloat16 h[4]; ushort4 u; } pk;
        pk.h[0] = __hip_bfloat16(v.x); pk.h[1] = __hip_bfloat16(v.y);
        pk.h[2] = __hip_bfloat16(v.z); pk.h[3] = __hip_bfloat16(v.w);
        *(ushort4*)(xb + i) = pk.u;
        return;
    }
    const float* in; __hip_bfloat16* out; int C, c0, r0;
    if (b < 7168) {
        int bb = b - 4096; in = wqkv; out = wqkvT; C = 3072;
        c0 = (bb % 96) * 32; r0 = (bb / 96) * 32;
    } else {
        int bb = b - 7168; in = wproj; out = wprojT; C = 1024;
        c0 = (bb & 31) * 32; r0 = (bb >> 5) * 32;
    }
    const int tx = threadIdx.x & 31, ty = threadIdx.x >> 5;
#pragma unroll
    for (int p = 0; p < 32; p += 8)
        tile[ty + p][tx] = in[(size_t)(r0 + ty + p) * C + c0 + tx];
    __syncthreads();
#pragma unroll
    for (int p = 0; p < 32; p += 8)
        out[(size_t)(c0 + ty + p) * 1024 + r0 + tx] = __hip_bfloat16(tile[tx][ty + p]);
}

// -------- GEMM1: 128x128 tile, BK=64 as two m97-style 32-wide sub-tiles --------
__global__ __launch_bounds__(256) void gemm_bt_128(
    const __hip_bfloat16* __restrict__ A,
    const __hip_bfloat16* __restrict__ Bt,
    __hip_bfloat16* __restrict__ C,
    int M, int N, int K)
{
    __shared__ __align__(16) __hip_bfloat16 As[2 * 128 * 32];
    __shared__ __align__(16) __hip_bfloat16 Bs[2 * 128 * 32];

    const int tid  = threadIdx.x;
    const int wv   = tid >> 6;
    const int lane = tid & 63;
    const int bn   = blockIdx.x, bm = blockIdx.y;
    const int wm   = wv >> 1, wn = wv & 1;

    f32x4 acc[4][4] = {};

    const int srow = lane >> 2;          // 0..15
    const int scol = (lane & 3) * 8;     // 16B per lane

    const __hip_bfloat16* Ag = A  + (size_t)(bm * 128) * K;
    const __hip_bfloat16* Bg = Bt + (size_t)(bn * 128) * K;

    const int fm = lane & 15;
    const int fq = (lane >> 4) * 8;

    for (int kk = 0; kk < K; kk += 64) {
#pragma unroll
        for (int kh = 0; kh < 2; ++kh)
#pragma unroll
            for (int it = 0; it < 2; ++it) {
                int row = (it * 4 + wv) * 16 + srow;          // 0..127
                gld_lds16(Ag + (size_t)row * K + kk + kh * 32 + scol,
                          As + kh * 4096 + row * 32 + scol);
                gld_lds16(Bg + (size_t)row * K + kk + kh * 32 + scol,
                          Bs + kh * 4096 + row * 32 + scol);
            }
        __syncthreads();

#pragma unroll
        for (int kh = 0; kh < 2; ++kh) {
            bf16x8 af[4], bfr[4];
#pragma unroll
            for (int i = 0; i < 4; ++i)
                af[i] = *(const bf16x8*)(As + kh * 4096 + (wm * 64 + i * 16 + fm) * 32 + fq);
#pragma unroll
            for (int j = 0; j < 4; ++j)
                bfr[j] = *(const bf16x8*)(Bs + kh * 4096 + (wn * 64 + j * 16 + fm) * 32 + fq);
#pragma unroll
            for (int i = 0; i < 4; ++i)
#pragma unroll
                for (int j = 0; j < 4; ++j)
                    acc[i][j] = __builtin_amdgcn_mfma_f32_16x16x32_bf16(af[i], bfr[j], acc[i][j], 0, 0, 0);
        }
        __syncthreads();
    }

    // C/D layout: col=lane&15, row=(lane>>4)*4+reg  [m89-verified]
    const int fcol  = lane & 15;
    const int frow4 = (lane >> 4) * 4;
    const int cm0 = bm * 128 + wm * 64;
    const int cn0 = bn * 128 + wn * 64;
#pragma unroll
    for (int j = 0; j < 4; ++j) {
        int col = cn0 + j * 16 + fcol;
#pragma unroll
        for (int i = 0; i < 4; ++i)
#pragma unroll
            for (int r = 0; r < 4; ++r) {
                int row = cm0 + i * 16 + frow4 + r;
                C[(size_t)row * N + col] = __hip_bfloat16(acc[i][j][r]);
            }
    }
}

// -------- GEMM2: 64x128 tile, BK=64 (512 blocks = 2/CU), fp32 out + bias --------
__global__ __launch_bounds__(256) void gemm_bt_64(
    const __hip_bfloat16* __restrict__ A,
    const __hip_bfloat16* __restrict__ Bt,
    const float* __restrict__ bias,
    float* __restrict__ C,
    int M, int N, int K)
{
    __shared__ __align__(16) __hip_bfloat16 As[2 * 64 * 32];
    __shared__ __align__(16) __hip_bfloat16 Bs[2 * 128 * 32];

    const int tid  = threadIdx.x;
    const int wv   = tid >> 6;
    const int lane = tid & 63;
    const int bn   = blockIdx.x, bm = blockIdx.y;
    const int wm   = wv >> 1, wn = wv & 1;

    f32x4 acc[2][4] = {};

    const int srow = lane >> 2;
    const int scol = (lane & 3) * 8;

    const __hip_bfloat16* Ag = A  + (size_t)(bm * 64) * K;
    const __hip_bfloat16* Bg = Bt + (size_t)(bn * 128) * K;

    const int fm = lane & 15;
    const int fq = (lane >> 4) * 8;

    for (int kk = 0; kk < K; kk += 64) {
#pragma unroll
        for (int kh = 0; kh < 2; ++kh) {
            {
                int row = wv * 16 + srow;                     // 0..63
                gld_lds16(Ag + (size_t)row * K + kk + kh * 32 + scol,
                          As + kh * 2048 + row * 32 + scol);
            }
#pragma unroll
            for (int it = 0; it < 2; ++it) {
                int row = (it * 4 + wv) * 16 + srow;          // 0..127
                gld_lds16(Bg + (size_t)row * K + kk + kh * 32 + scol,
                          Bs + kh * 4096 + row * 32 + scol);
            }
        }
        __syncthreads();

#pragma unroll
        for (int kh = 0; kh < 2; ++kh) {
            bf16x8 af[2], bfr[4];
#pragma unroll
            for (int i = 0; i < 2; ++i)
                af[i] = *(const bf16x8*)(As + kh * 2048 + (wm * 32 + i * 16 + fm) * 32 + fq);
#pragma unroll
            for (int j = 0; j < 4; ++j)
                bfr[j] = *(const bf16x8*)(Bs + kh * 4096 + (wn * 64 + j * 16 + fm) * 32 + fq);
#pragma unroll
            for (int i = 0; i < 2; ++i)
#pragma unroll
                for (int j = 0; j < 4; ++j)
                    acc[i][j] = __builtin_amdgcn_mfma_f32_16x16x32_bf16(af[i], bfr[j], acc[i][j], 0, 0, 0);
        }
        __syncthreads();
    }

    const int fcol  = lane & 15;
    const int frow4 = (lane >> 4) * 4;
    const int cm0 = bm * 64 + wm * 32;
    const int cn0 = bn * 128 + wn * 64;
#pragma unroll
    for (int j = 0; j < 4; ++j) {
        int col = cn0 + j * 16 + fcol;
        float bv = bias[col];
#pragma unroll
        for (int i = 0; i < 2; ++i)
#pragma unroll
            for (int r = 0; r < 4; ++r) {
                int row = cm0 + i * 16 + frow4 + r;
                C[(size_t)row * N + col] = acc[i][j][r] + bv;
            }
    }
}

// -------- banded attention, vectorized: one block per token, thread = 4-dim chunk --------
__global__ __launch_bounds__(256) void attn_banded(
    const __hip_bfloat16* __restrict__ qkv,   // (B*T, 3*DIM): [q | k | v]
    __hip_bfloat16* __restrict__ o)           // (B*T, DIM)
{
    const int t4 = threadIdx.x;          // dim-chunk index: dims [4*t4, 4*t4+4)
    const int r  = blockIdx.x;           // b*T + t
    const int t  = r & (T_SEQ - 1);
    const size_t rb = (size_t)r * (3 * DIMSZ);
    const int d0 = t4 * 4;

    ushort4 qu = *(const ushort4*)(qkv + rb + d0);
    float q0 = bf2f(qu.x), q1 = bf2f(qu.y), q2 = bf2f(qu.z), q3 = bf2f(qu.w);

    float s[3], vvx[3], vvy[3], vvz[3], vvw[3];
#pragma unroll
    for (int j = 0; j < 3; ++j) {
        bool ok = (t + j) < T_SEQ;       // masks seq end (and batch boundary)
        size_t rbj = ok ? rb + (size_t)j * (3 * DIMSZ) : rb;
        ushort4 ku = *(const ushort4*)(qkv + rbj + DIMSZ + d0);
        ushort4 vu = *(const ushort4*)(qkv + rbj + 2 * DIMSZ + d0);
        vvx[j] = bf2f(vu.x); vvy[j] = bf2f(vu.y); vvz[j] = bf2f(vu.z); vvw[j] = bf2f(vu.w);
        float d = q0 * bf2f(ku.x) + q1 * bf2f(ku.y) + q2 * bf2f(ku.z) + q3 * bf2f(ku.w);
#pragma unroll
        for (int off = 8; off > 0; off >>= 1)
            d += __shfl_xor(d, off, 64); // reduce within 16-lane head group
        s[j] = ok ? d * 0.125f : -1e30f; // scale = 64^-0.5
    }
    float m  = fmaxf(s[0], fmaxf(s[1], s[2]));
    float p0 = __expf(s[0] - m), p1 = __expf(s[1] - m), p2 = __expf(s[2] - m);
    float inv = 1.0f / (p0 + p1 + p2);
    union { __hip_bfloat16 h[4]; ushort4 uu; } pk;
    pk.h[0] = __hip_bfloat16((p0 * vvx[0] + p1 * vvx[1] + p2 * vvx[2]) * inv);
    pk.h[1] = __hip_bfloat16((p0 * vvy[0] + p1 * vvy[1] + p2 * vvy[2]) * inv);
    pk.h[2] = __hip_bfloat16((p0 * vvz[0] + p1 * vvz[1] + p2 * vvz[2]) * inv);
    pk.h[3] = __hip_bfloat16((p0 * vvw[0] + p1 * vvw[1] + p2 * vvw[2]) * inv);
    *(ushort4*)(o + (size_t)r * DIMSZ + d0) = pk.uu;
}

extern "C" void kernel_launch(void* const* d_in, const int* in_sizes, int n_in,
                              void* d_out, int out_size, void* d_ws, size_t ws_size,
                              hipStream_t stream) {
    const float* x      = (const float*)d_in[0];  // (B,T,DIM) fp32
    const float* w_qkv  = (const float*)d_in[1];  // (DIM, 3*DIM) fp32
    const float* w_proj = (const float*)d_in[2];  // (DIM, DIM) fp32
    const float* b_proj = (const float*)d_in[3];  // (DIM,) fp32
    float* out = (float*)d_out;                   // (B,T,DIM) fp32

    const int M = NBATCH * T_SEQ;   // 4096

    // workspace (bf16 intermediates):
    //   [0,8M)    xb (x bf16) -> reused as attn output after GEMM1 consumes it
    //   [8M,14M)  wqkvT  (3072x1024)
    //   [14M,16M) wprojT (1024x1024)
    //   [16M,40M) qkv    (4096x3072)
    char* ws = (char*)d_ws;
    __hip_bfloat16* xb     = (__hip_bfloat16*)(ws);
    __hip_bfloat16* attn   = (__hip_bfloat16*)(ws);            // reuse of xb region
    __hip_bfloat16* wqkvT  = (__hip_bfloat16*)(ws + (8u  << 20));
    __hip_bfloat16* wprojT = (__hip_bfloat16*)(ws + (14u << 20));
    __hip_bfloat16* qkv    = (__hip_bfloat16*)(ws + (16u << 20));

    // 1) fused prep: x->bf16, both weight convert+transposes
    prep<<<8192, 256, 0, stream>>>(x, xb, w_qkv, wqkvT, w_proj, wprojT);

    // 2) qkv = x @ w_qkv   (4096 x 3072, K=1024): 24x32=768 blocks = 3/CU
    gemm_bt_128<<<dim3(3 * DIMSZ / 128, M / 128), 256, 0, stream>>>(
        xb, wqkvT, qkv, M, 3 * DIMSZ, DIMSZ);

    // 3) banded attention (3-key window) -> bf16 attn (reuses xb region)
    attn_banded<<<M, 256, 0, stream>>>(qkv, attn);

    // 4) out = attn @ w_proj + b_proj  (4096 x 1024): 8x64=512 blocks = 2/CU
    gemm_bt_64<<<dim3(DIMSZ / 128, M / 64), 256, 0, stream>>>(
        attn, wprojT, b_proj, out, M, DIMSZ, DIMSZ);
}